// Round 1
// baseline (389.728 us; speedup 1.0000x reference)
//
#include <hip/hip_runtime.h>

// Causal linear attention (elu+1 feature map), chunk-parallel decomposition.
// Shapes fixed by the reference: N=4, L=4096, H=12, D=M=64.

#define NBATCH 4
#define LSEQ   4096
#define NHEAD  12
#define DDIM   64
#define LSTRIDE (NHEAD * DDIM)   // floats between consecutive l for fixed (n,h)
#define NH     (NBATCH * NHEAD)  // 48 independent sequences
#define EPSF   1e-6f

__device__ __forceinline__ float phi(float x) {
    // elu(x) + 1  ==  x > 0 ? x + 1 : exp(x)
    return x > 0.0f ? x + 1.0f : __expf(x);
}

// ---------------------------------------------------------------------------
// Kernel 1: per-(seq,chunk) sums:  KV[d][m] = sum_{l in chunk} phi(k)[d] * v[m]
//           Ksum[d] = sum_{l in chunk} phi(k)[d]
// One wave (64 threads) per chunk. Lane m owns KV column m in registers.
// ---------------------------------------------------------------------------
template<int C>
__global__ __launch_bounds__(64) void k_chunksum(const float* __restrict__ kin,
                                                 const float* __restrict__ vin,
                                                 float* __restrict__ kv,
                                                 float* __restrict__ ksum) {
    constexpr int numC = LSEQ / C;
    const int b    = blockIdx.x;        // seq * numC + c
    const int seq  = b / numC;          // n*NHEAD + h
    const int c    = b % numC;
    const int n    = seq / NHEAD;
    const int h    = seq % NHEAD;
    const int lane = threadIdx.x;       // 0..63

    int base = ((n * LSEQ + c * C) * NHEAD + h) * DDIM + lane;

    float kvcol[DDIM];
#pragma unroll
    for (int d = 0; d < DDIM; ++d) kvcol[d] = 0.0f;
    float ks = 0.0f;

    __shared__ float krow[DDIM];

    for (int i = 0; i < C; ++i) {
        float kval = phi(kin[base]);
        float vval = vin[base];
        base += LSTRIDE;
        ks += kval;
        krow[lane] = kval;
        __syncthreads();
        const float4* kr4 = (const float4*)krow;
#pragma unroll
        for (int d4 = 0; d4 < DDIM / 4; ++d4) {
            float4 kk = kr4[d4];            // broadcast LDS read (conflict-free)
            kvcol[4 * d4 + 0] += kk.x * vval;
            kvcol[4 * d4 + 1] += kk.y * vval;
            kvcol[4 * d4 + 2] += kk.z * vval;
            kvcol[4 * d4 + 3] += kk.w * vval;
        }
        __syncthreads();
    }

#pragma unroll
    for (int d = 0; d < DDIM; ++d)
        kv[(b * DDIM + d) * DDIM + lane] = kvcol[d];   // coalesced over lane
    ksum[b * DDIM + lane] = ks;
}

// ---------------------------------------------------------------------------
// Kernel 2: in-place exclusive prefix scan over chunks, per sequence.
// One block (256 threads) per sequence; thread t owns elements t + 256*j.
// ---------------------------------------------------------------------------
template<int C>
__global__ __launch_bounds__(256) void k_scan(float* __restrict__ kv,
                                              float* __restrict__ ksum) {
    constexpr int numC = LSEQ / C;
    const int seq = blockIdx.x;
    const int t   = threadIdx.x;

    float S[16];
#pragma unroll
    for (int j = 0; j < 16; ++j) S[j] = 0.0f;
    float ks = 0.0f;

    for (int c = 0; c < numC; ++c) {
        int off = (seq * numC + c) * (DDIM * DDIM);
#pragma unroll
        for (int j = 0; j < 16; ++j) {
            int idx = off + t + 256 * j;
            float tmp = kv[idx];
            kv[idx] = S[j];               // store exclusive prefix
            S[j] += tmp;
        }
        if (t < DDIM) {
            int o2 = (seq * numC + c) * DDIM + t;
            float tmp = ksum[o2];
            ksum[o2] = ks;
            ks += tmp;
        }
    }
}

// ---------------------------------------------------------------------------
// Kernel 3: per-(seq,chunk) output. Lane m owns running state column m.
// Per step: Scol += phi(k)[d]*v[m]; o[m] = sum_d phi(q)[d]*Scol[d];
//           z = phi(q) . Kcum  (wave butterfly reduce); out = o / z.
// ---------------------------------------------------------------------------
template<int C>
__global__ __launch_bounds__(64) void k_out(const float* __restrict__ qin,
                                            const float* __restrict__ kin,
                                            const float* __restrict__ vin,
                                            const float* __restrict__ kv,
                                            const float* __restrict__ ksum,
                                            float* __restrict__ out) {
    constexpr int numC = LSEQ / C;
    const int b    = blockIdx.x;
    const int seq  = b / numC;
    const int c    = b % numC;
    const int n    = seq / NHEAD;
    const int h    = seq % NHEAD;
    const int lane = threadIdx.x;

    // Load exclusive-prefix state column m (coalesced over lane per d).
    float Scol[DDIM];
#pragma unroll
    for (int d = 0; d < DDIM; ++d)
        Scol[d] = kv[(b * DDIM + d) * DDIM + lane];
    float kc = ksum[b * DDIM + lane];   // lane acts as d for the normalizer

    __shared__ float qk[2 * DDIM];      // interleaved (k, q) row

    int base = ((n * LSEQ + c * C) * NHEAD + h) * DDIM + lane;

    for (int i = 0; i < C; ++i) {
        float qval = phi(qin[base]);
        float kval = phi(kin[base]);
        float vval = vin[base];

        // normalizer: z = sum_d q[d] * Kcum[d] (inclusive of current l)
        kc += kval;
        float zp = qval * kc;
#pragma unroll
        for (int off = 32; off > 0; off >>= 1)
            zp += __shfl_xor(zp, off, 64);
        float z = zp + EPSF;

        qk[2 * lane]     = kval;
        qk[2 * lane + 1] = qval;
        __syncthreads();

        const float4* qk4 = (const float4*)qk;
        float a0 = 0.0f, a1 = 0.0f, a2 = 0.0f, a3 = 0.0f;
#pragma unroll
        for (int d2 = 0; d2 < DDIM / 2; d2 += 2) {
            float4 t0 = qk4[d2];        // (k[d],q[d],k[d+1],q[d+1])
            float4 t1 = qk4[d2 + 1];
            int d = 2 * d2;
            Scol[d]     += t0.x * vval;  a0 += t0.y * Scol[d];
            Scol[d + 1] += t0.z * vval;  a1 += t0.w * Scol[d + 1];
            Scol[d + 2] += t1.x * vval;  a2 += t1.y * Scol[d + 2];
            Scol[d + 3] += t1.z * vval;  a3 += t1.w * Scol[d + 3];
        }

        out[base] = (a0 + a1 + a2 + a3) / z;   // same layout as inputs (M==D)
        base += LSTRIDE;
        __syncthreads();
    }
}

// ---------------------------------------------------------------------------
// Host launcher
// ---------------------------------------------------------------------------
template<int C>
static void run_all(const float* q, const float* k, const float* v, float* out,
                    float* ws, hipStream_t stream) {
    constexpr int numC = LSEQ / C;
    float* kv   = ws;
    float* ksum = ws + (size_t)NH * numC * DDIM * DDIM;
    k_chunksum<C><<<NH * numC, 64, 0, stream>>>(k, v, kv, ksum);
    k_scan<C><<<NH, 256, 0, stream>>>(kv, ksum);
    k_out<C><<<NH * numC, 64, 0, stream>>>(q, k, v, kv, ksum, out);
}

static size_t ws_need(int numC) {
    return (size_t)NH * numC * (DDIM * DDIM + DDIM) * sizeof(float);
}

extern "C" void kernel_launch(void* const* d_in, const int* in_sizes, int n_in,
                              void* d_out, int out_size, void* d_ws, size_t ws_size,
                              hipStream_t stream) {
    const float* q = (const float*)d_in[0];
    const float* k = (const float*)d_in[1];
    const float* v = (const float*)d_in[2];
    float* out = (float*)d_out;
    float* ws  = (float*)d_ws;

    if (ws_size >= ws_need(LSEQ / 64)) {
        run_all<64>(q, k, v, out, ws, stream);
    } else if (ws_size >= ws_need(LSEQ / 128)) {
        run_all<128>(q, k, v, out, ws, stream);
    } else if (ws_size >= ws_need(LSEQ / 256)) {
        run_all<256>(q, k, v, out, ws, stream);
    } else if (ws_size >= ws_need(LSEQ / 512)) {
        run_all<512>(q, k, v, out, ws, stream);
    } else {
        run_all<4096>(q, k, v, out, ws, stream);  // numC=1: fully sequential fallback
    }
}

// Round 2
// 268.025 us; speedup vs baseline: 1.4541x; 1.4541x over previous
//
#include <hip/hip_runtime.h>

// Causal linear attention (elu+1 feature map) — chunked matmul formulation.
// N=4, L=4096, H=12, D=M=64.  Per chunk of C=64:
//   A = Qf Kf^T (causal-masked);  O = A_masked V + Qf S_prefix
//   z = Qf Ksum_prefix + rowsum(A_masked)
// 3 kernels: per-chunk KV/Ksum sums -> exclusive chunk scan -> per-chunk output.

#define NBATCH 4
#define LSEQ   4096
#define NHEAD  12
#define DDIM   64
#define LSTRIDE (NHEAD * DDIM)
#define NH     (NBATCH * NHEAD)
#define EPSF   1e-6f
#define CHUNK  64
#define NUMC   (LSEQ / CHUNK)
#define PAD    68        // LDS row stride in floats (64+4: 16B-aligned, kills conflicts)

__device__ __forceinline__ float phi(float x) {
    return x > 0.0f ? x + 1.0f : __expf(x);
}

// ---------------------------------------------------------------------------
// Kernel 1: per-chunk KV[d][m] = sum_l Kf[l][d] V[l][m], Ksum[d] = sum_l Kf[l][d]
// 256 threads, 4x4 register tile per thread.
// ---------------------------------------------------------------------------
__global__ __launch_bounds__(256) void k_chunksum_mm(const float* __restrict__ kin,
                                                     const float* __restrict__ vin,
                                                     float* __restrict__ kv,
                                                     float* __restrict__ ksum) {
    __shared__ float sK[CHUNK * PAD];   // [l][d], phi applied
    __shared__ float sV[CHUNK * PAD];   // [l][m]
    const int b = blockIdx.x, seq = b / NUMC, c = b % NUMC;
    const int n = seq / NHEAD, h = seq % NHEAD;
    const int t = threadIdx.x;
    const int gbase = ((n * LSEQ + c * CHUNK) * NHEAD + h) * DDIM;

#pragma unroll
    for (int rep = 0; rep < 4; ++rep) {
        int flat = rep * 256 + t;
        int l = flat >> 4, c4 = (flat & 15) << 2;
        const float4 kk = *(const float4*)(kin + gbase + l * LSTRIDE + c4);
        const float4 vv = *(const float4*)(vin + gbase + l * LSTRIDE + c4);
        float4 kf;
        kf.x = phi(kk.x); kf.y = phi(kk.y); kf.z = phi(kk.z); kf.w = phi(kk.w);
        *(float4*)(sK + l * PAD + c4) = kf;
        *(float4*)(sV + l * PAD + c4) = vv;
    }
    __syncthreads();

    const int ty = t >> 4, tx = t & 15;
    float acc[4][4];
#pragma unroll
    for (int i = 0; i < 4; ++i)
#pragma unroll
        for (int j = 0; j < 4; ++j) acc[i][j] = 0.0f;
    float ks[4] = {0.f, 0.f, 0.f, 0.f};

#pragma unroll 8
    for (int l = 0; l < CHUNK; ++l) {
        float4 ka = *(const float4*)(sK + l * PAD + 4 * ty);
        float4 va = *(const float4*)(sV + l * PAD + 4 * tx);
        float karr[4] = {ka.x, ka.y, ka.z, ka.w};
        float varr[4] = {va.x, va.y, va.z, va.w};
#pragma unroll
        for (int i = 0; i < 4; ++i) {
            ks[i] += karr[i];
#pragma unroll
            for (int j = 0; j < 4; ++j) acc[i][j] += karr[i] * varr[j];
        }
    }

    float* kvb = kv + (size_t)b * DDIM * DDIM;
#pragma unroll
    for (int i = 0; i < 4; ++i) {
        float4 st = {acc[i][0], acc[i][1], acc[i][2], acc[i][3]};
        *(float4*)(kvb + (4 * ty + i) * DDIM + 4 * tx) = st;
    }
    if (tx == 0) {
#pragma unroll
        for (int i = 0; i < 4; ++i) ksum[b * DDIM + 4 * ty + i] = ks[i];
    }
}

// ---------------------------------------------------------------------------
// Kernel 2: exclusive prefix scan over chunks. One float4 column per thread.
// Grid: NH*16 blocks of 64 threads.
// ---------------------------------------------------------------------------
__global__ __launch_bounds__(64) void k_scan_mm(float* __restrict__ kv,
                                                float* __restrict__ ksum) {
    const int bid = blockIdx.x;
    const int seq = bid >> 4, part = bid & 15;
    const int t = threadIdx.x;
    float4* base = (float4*)(kv + (size_t)seq * NUMC * DDIM * DDIM) + part * 64 + t;
    float4 S = {0.f, 0.f, 0.f, 0.f};
#pragma unroll 4
    for (int c = 0; c < NUMC; ++c) {
        float4 x = base[c * (DDIM * DDIM / 4)];
        base[c * (DDIM * DDIM / 4)] = S;
        S.x += x.x; S.y += x.y; S.z += x.z; S.w += x.w;
    }
    if (part == 0) {
        float s = 0.0f;
        float* kb = ksum + (size_t)seq * NUMC * DDIM + t;
        for (int c = 0; c < NUMC; ++c) {
            float x = kb[c * DDIM];
            kb[c * DDIM] = s;
            s += x;
        }
    }
}

// ---------------------------------------------------------------------------
// Kernel 3: per-chunk output via three 64^3 matmuls + fused normalizer.
// ---------------------------------------------------------------------------
__global__ __launch_bounds__(256) void k_out_mm(const float* __restrict__ qin,
                                                const float* __restrict__ kin,
                                                const float* __restrict__ vin,
                                                const float* __restrict__ kv,
                                                const float* __restrict__ ksum,
                                                float* __restrict__ out) {
    __shared__ float sQT[DDIM * PAD];   // [d][l]  (phi(q) transposed)
    __shared__ float sKT[DDIM * PAD];   // [d][l]  -> reused as AT [j][i]
    __shared__ float sV [CHUNK * PAD];  // [l][m]
    __shared__ float sKs[DDIM];
    __shared__ float sZ [CHUNK];

    const int b = blockIdx.x, seq = b / NUMC, c = b % NUMC;
    const int n = seq / NHEAD, h = seq % NHEAD;
    const int t = threadIdx.x;
    const int gbase = ((n * LSEQ + c * CHUNK) * NHEAD + h) * DDIM;

    if (t < DDIM) sKs[t] = ksum[b * DDIM + t];
#pragma unroll
    for (int rep = 0; rep < 4; ++rep) {
        int flat = rep * 256 + t;
        int l = flat >> 4, c4 = (flat & 15) << 2;
        const float4 qq = *(const float4*)(qin + gbase + l * LSTRIDE + c4);
        const float4 kk = *(const float4*)(kin + gbase + l * LSTRIDE + c4);
        const float4 vv = *(const float4*)(vin + gbase + l * LSTRIDE + c4);
        sQT[(c4 + 0) * PAD + l] = phi(qq.x);
        sQT[(c4 + 1) * PAD + l] = phi(qq.y);
        sQT[(c4 + 2) * PAD + l] = phi(qq.z);
        sQT[(c4 + 3) * PAD + l] = phi(qq.w);
        sKT[(c4 + 0) * PAD + l] = phi(kk.x);
        sKT[(c4 + 1) * PAD + l] = phi(kk.y);
        sKT[(c4 + 2) * PAD + l] = phi(kk.z);
        sKT[(c4 + 3) * PAD + l] = phi(kk.w);
        *(float4*)(sV + l * PAD + c4) = vv;
    }
    __syncthreads();

    const int ty = t >> 4, tx = t & 15;

    // Phase A: A[i][j] = sum_d Qf[i][d] Kf[j][d];  zq[i] = sum_d Qf[i][d] Ksum[d]
    float a[4][4];
#pragma unroll
    for (int i = 0; i < 4; ++i)
#pragma unroll
        for (int j = 0; j < 4; ++j) a[i][j] = 0.0f;
    float zq[4] = {0.f, 0.f, 0.f, 0.f};

#pragma unroll 4
    for (int d = 0; d < DDIM; ++d) {
        float4 qv4 = *(const float4*)(sQT + d * PAD + 4 * ty);
        float4 kv4 = *(const float4*)(sKT + d * PAD + 4 * tx);
        float ksd = sKs[d];
        float qa[4] = {qv4.x, qv4.y, qv4.z, qv4.w};
        float ka[4] = {kv4.x, kv4.y, kv4.z, kv4.w};
#pragma unroll
        for (int i = 0; i < 4; ++i) {
            zq[i] += qa[i] * ksd;
#pragma unroll
            for (int j = 0; j < 4; ++j) a[i][j] += qa[i] * ka[j];
        }
    }

    // masked rowsum of A, reduced across the 16 tx lanes
    float zrow[4];
#pragma unroll
    for (int i = 0; i < 4; ++i) {
        int row = 4 * ty + i;
        float rs = 0.0f;
#pragma unroll
        for (int j = 0; j < 4; ++j)
            if (4 * tx + j <= row) rs += a[i][j];
#pragma unroll
        for (int m = 1; m < 16; m <<= 1) rs += __shfl_xor(rs, m, 16);
        zrow[i] = rs;
    }
    __syncthreads();   // all A-phase reads of sKT complete

    if (tx == 0) {
#pragma unroll
        for (int i = 0; i < 4; ++i) sZ[4 * ty + i] = zrow[i] + zq[i] + EPSF;
    }
    // store masked A transposed into sKT:  AT[j][i] = A[i][j]
#pragma unroll
    for (int j = 0; j < 4; ++j) {
        int col = 4 * tx + j;
#pragma unroll
        for (int i = 0; i < 4; ++i) {
            int row = 4 * ty + i;
            sKT[col * PAD + row] = (col <= row) ? a[i][j] : 0.0f;
        }
    }
    __syncthreads();

    float o[4][4];
#pragma unroll
    for (int i = 0; i < 4; ++i)
#pragma unroll
        for (int j = 0; j < 4; ++j) o[i][j] = 0.0f;

    // O_intra = A_masked V
#pragma unroll 4
    for (int j = 0; j < CHUNK; ++j) {
        float4 av = *(const float4*)(sKT + j * PAD + 4 * ty);
        float4 vv = *(const float4*)(sV + j * PAD + 4 * tx);
        float aa[4] = {av.x, av.y, av.z, av.w};
        float va[4] = {vv.x, vv.y, vv.z, vv.w};
#pragma unroll
        for (int i = 0; i < 4; ++i)
#pragma unroll
            for (int jj = 0; jj < 4; ++jj) o[i][jj] += aa[i] * va[jj];
    }

    // O_inter = Qf S_prefix  (S read from global, hits L1/L2: 16 KB/block)
    const float* Sg = kv + (size_t)b * DDIM * DDIM;
#pragma unroll 4
    for (int d = 0; d < DDIM; ++d) {
        float4 qv4 = *(const float4*)(sQT + d * PAD + 4 * ty);
        float4 sv4 = *(const float4*)(Sg + d * DDIM + 4 * tx);
        float qa[4] = {qv4.x, qv4.y, qv4.z, qv4.w};
        float sa[4] = {sv4.x, sv4.y, sv4.z, sv4.w};
#pragma unroll
        for (int i = 0; i < 4; ++i)
#pragma unroll
            for (int j = 0; j < 4; ++j) o[i][j] += qa[i] * sa[j];
    }

#pragma unroll
    for (int i = 0; i < 4; ++i) {
        int row = 4 * ty + i;
        float invz = 1.0f / sZ[row];
        float4 st = {o[i][0] * invz, o[i][1] * invz, o[i][2] * invz, o[i][3] * invz};
        *(float4*)(out + gbase + row * LSTRIDE + 4 * tx) = st;
    }
}

// ---------------------------------------------------------------------------
// Fallback (tiny ws): fully sequential per-sequence scan, no workspace.
// ---------------------------------------------------------------------------
__global__ __launch_bounds__(64) void k_seq(const float* __restrict__ qin,
                                            const float* __restrict__ kin,
                                            const float* __restrict__ vin,
                                            float* __restrict__ out) {
    const int seq = blockIdx.x;
    const int n = seq / NHEAD, h = seq % NHEAD;
    const int lane = threadIdx.x;
    float Scol[DDIM];
#pragma unroll
    for (int d = 0; d < DDIM; ++d) Scol[d] = 0.0f;
    float kc = 0.0f;
    __shared__ float qk[2 * DDIM];
    int base = (n * LSEQ * NHEAD + h) * DDIM + lane;
    for (int i = 0; i < LSEQ; ++i) {
        float qval = phi(qin[base]);
        float kval = phi(kin[base]);
        float vval = vin[base];
        kc += kval;
        float zp = qval * kc;
#pragma unroll
        for (int off = 32; off > 0; off >>= 1) zp += __shfl_xor(zp, off, 64);
        float z = zp + EPSF;
        qk[2 * lane] = kval;
        qk[2 * lane + 1] = qval;
        __syncthreads();
        const float4* qk4 = (const float4*)qk;
        float acc = 0.0f;
#pragma unroll
        for (int d2 = 0; d2 < DDIM / 2; ++d2) {
            float4 t0 = qk4[d2];
            int d = 2 * d2;
            Scol[d]     += t0.x * vval;  acc += t0.y * Scol[d];
            Scol[d + 1] += t0.z * vval;  acc += t0.w * Scol[d + 1];
        }
        out[base] = acc / z;
        base += LSTRIDE;
        __syncthreads();
    }
}

// ---------------------------------------------------------------------------
extern "C" void kernel_launch(void* const* d_in, const int* in_sizes, int n_in,
                              void* d_out, int out_size, void* d_ws, size_t ws_size,
                              hipStream_t stream) {
    const float* q = (const float*)d_in[0];
    const float* k = (const float*)d_in[1];
    const float* v = (const float*)d_in[2];
    float* out = (float*)d_out;
    float* ws  = (float*)d_ws;

    const size_t need = (size_t)NH * NUMC * (DDIM * DDIM + DDIM) * sizeof(float);
    if (ws_size >= need) {
        float* kv   = ws;
        float* ksum = ws + (size_t)NH * NUMC * DDIM * DDIM;
        k_chunksum_mm<<<NH * NUMC, 256, 0, stream>>>(k, v, kv, ksum);
        k_scan_mm<<<NH * 16, 64, 0, stream>>>(kv, ksum);
        k_out_mm<<<NH * NUMC, 256, 0, stream>>>(q, k, v, kv, ksum, out);
    } else {
        k_seq<<<NH, 64, 0, stream>>>(q, k, v, out);
    }
}

// Round 3
// 224.186 us; speedup vs baseline: 1.7384x; 1.1955x over previous
//
#include <hip/hip_runtime.h>

// Causal linear attention (elu+1 feature map) — chunked MFMA formulation.
// N=4, L=4096, H=12, D=M=64. Per chunk of C=64 (all matmuls bf16 MFMA, fp32 acc):
//   A = Qf Kf^T (causal-masked);  O = Amask V + Qf S_prefix
//   z = rowsum(Amask) + Qf Ksum_prefix
// kernels: chunk sums (KV^T, Ksum) -> exclusive chunk scan -> per-chunk output.

#define NBATCH 4
#define LSEQ   4096
#define NHEAD  12
#define DDIM   64
#define LSTRIDE (NHEAD * DDIM)
#define NH     (NBATCH * NHEAD)
#define EPSF   1e-6f
#define CHUNK  64
#define NUMC   (LSEQ / CHUNK)
#define SB     72      // LDS row stride in shorts (144B: 16B-aligned frags, 2-way banks)

typedef __attribute__((ext_vector_type(8))) short bf16x8;
typedef __attribute__((ext_vector_type(4))) float f32x4;

__device__ __forceinline__ float phi(float x) { return x > 0.f ? x + 1.f : __expf(x); }

__device__ __forceinline__ unsigned short f2bf(float x) {
    union { float f; unsigned u; } v; v.f = x;
    unsigned r = v.u + 0x7fffu + ((v.u >> 16) & 1u);   // RNE
    return (unsigned short)(r >> 16);
}
__device__ __forceinline__ float bf2f(short s) {
    union { float f; unsigned u; } v; v.u = ((unsigned)(unsigned short)s) << 16;
    return v.f;
}
__device__ __forceinline__ uint2 pack4(float4 a) {
    uint2 r;
    r.x = (unsigned)f2bf(a.x) | ((unsigned)f2bf(a.y) << 16);
    r.y = (unsigned)f2bf(a.z) | ((unsigned)f2bf(a.w) << 16);
    return r;
}

// 4x4 fp32 transpose among lanes {lane^16, lane^32}: lane m' holds row l0+m' (4 cols)
// -> returns col c4+m' (4 rows). out[m][e] = in[e][m].
__device__ __forceinline__ float4 xpose4(float4 x, int lane) {
    const bool b0 = (lane >> 4) & 1, b1 = (lane >> 5) & 1;
    float s0 = b0 ? x.x : x.y;
    float s1 = b0 ? x.z : x.w;
    s0 = __shfl_xor(s0, 16);
    s1 = __shfl_xor(s1, 16);
    float4 y;
    if (b0) { y.x = s0;  y.y = x.y; y.z = s1;  y.w = x.w; }
    else    { y.x = x.x; y.y = s0;  y.z = x.z; y.w = s1;  }
    float t0 = b1 ? y.x : y.z;
    float t1 = b1 ? y.y : y.w;
    t0 = __shfl_xor(t0, 32);
    t1 = __shfl_xor(t1, 32);
    float4 z;
    if (b1) { z.x = t0;  z.y = t1;  z.z = y.z; z.w = y.w; }
    else    { z.x = y.x; z.y = y.y; z.z = t0;  z.w = t1;  }
    return z;
}

// ---------------------------------------------------------------------------
// Kernel 1: per-chunk KV^T[m][d] = sum_l V[l][m] Kf[l][d]  (so ws is S^T layout),
//           Ksum[d] = sum_l Kf[l][d].  4 waves, 8 MFMAs/wave.
// ---------------------------------------------------------------------------
__global__ __launch_bounds__(256) void k_sum_mf(const float* __restrict__ kin,
                                                const float* __restrict__ vin,
                                                float* __restrict__ kvws,
                                                float* __restrict__ ksws) {
    __shared__ short sKT[64 * SB];   // [d][l]
    __shared__ short sVT[64 * SB];   // [m][l]
    const int b = blockIdx.x, seq = b / NUMC, c = b % NUMC;
    const int n0 = seq / NHEAD, h0 = seq % NHEAD;
    const int t = threadIdx.x;
    const int gbase = ((n0 * LSEQ + c * CHUNK) * NHEAD + h0) * DDIM;
    const int lane = t & 63, w = t >> 6;
    const int nn = lane & 15, qq = lane >> 4;

#pragma unroll
    for (int rep = 0; rep < 4; ++rep) {
        const int row = rep * 16 + 4 * w + qq;   // l
        const int c4 = nn << 2;
        const int l0 = rep * 16 + 4 * w;
        float4 kk = *(const float4*)(kin + gbase + row * LSTRIDE + c4);
        float4 kp = {phi(kk.x), phi(kk.y), phi(kk.z), phi(kk.w)};
        float4 kt = xpose4(kp, lane);
        *(uint2*)(sKT + (c4 + qq) * SB + l0) = pack4(kt);
        float4 vv = *(const float4*)(vin + gbase + row * LSTRIDE + c4);
        float4 vt = xpose4(vv, lane);
        *(uint2*)(sVT + (c4 + qq) * SB + l0) = pack4(vt);
    }
    __syncthreads();

    const int rowM = 16 * w + nn;    // m (output row band of this wave)
    bf16x8 af0 = *(const bf16x8*)(sVT + rowM * SB + qq * 8);
    bf16x8 af1 = *(const bf16x8*)(sVT + rowM * SB + 32 + qq * 8);
    float* kvb = kvws + (size_t)b * DDIM * DDIM;
    float ks = 0.f;

#pragma unroll
    for (int ct = 0; ct < 4; ++ct) {
        bf16x8 bf0 = *(const bf16x8*)(sKT + (16 * ct + nn) * SB + qq * 8);
        bf16x8 bf1 = *(const bf16x8*)(sKT + (16 * ct + nn) * SB + 32 + qq * 8);
        f32x4 acc = {0.f, 0.f, 0.f, 0.f};
        acc = __builtin_amdgcn_mfma_f32_16x16x32_bf16(af0, bf0, acc, 0, 0, 0);
        acc = __builtin_amdgcn_mfma_f32_16x16x32_bf16(af1, bf1, acc, 0, 0, 0);
        if (ct == w) {   // wave-uniform: compute Ksum for d-band 16w..16w+15
            float s = 0.f;
#pragma unroll
            for (int j = 0; j < 8; ++j) s += bf2f(bf0[j]) + bf2f(bf1[j]);
            s += __shfl_xor(s, 16);
            s += __shfl_xor(s, 32);
            ks = s;      // Ksum[16w+nn] on every lane
        }
#pragma unroll
        for (int r = 0; r < 4; ++r)
            kvb[(16 * w + 4 * qq + r) * DDIM + 16 * ct + nn] = acc[r];
    }
    if (qq == 0) ksws[b * DDIM + 16 * w + nn] = ks;
}

// ---------------------------------------------------------------------------
// Kernel 2: exclusive prefix scan over chunks (elementwise, layout-agnostic).
// ---------------------------------------------------------------------------
__global__ __launch_bounds__(64) void k_scan_mm(float* __restrict__ kv,
                                                float* __restrict__ ksum) {
    const int bid = blockIdx.x;
    const int seq = bid >> 4, part = bid & 15;
    const int t = threadIdx.x;
    float4* base = (float4*)(kv + (size_t)seq * NUMC * DDIM * DDIM) + part * 64 + t;
    float4 S = {0.f, 0.f, 0.f, 0.f};
#pragma unroll 4
    for (int c = 0; c < NUMC; ++c) {
        float4 x = base[c * (DDIM * DDIM / 4)];
        base[c * (DDIM * DDIM / 4)] = S;
        S.x += x.x; S.y += x.y; S.z += x.z; S.w += x.w;
    }
    if (part == 0) {
        float s = 0.0f;
        float* kb = ksum + (size_t)seq * NUMC * DDIM + t;
        for (int c = 0; c < NUMC; ++c) {
            float x = kb[c * DDIM];
            kb[c * DDIM] = s;
            s += x;
        }
    }
}

// ---------------------------------------------------------------------------
// Kernel 3: per-chunk output. Phase A: A = Qf Kf^T (mask+rowsum). Phase B/C:
// O = Amask V + Qf S.  z = rowsum + Qf.Ksum.  24 MFMAs/wave.
// ---------------------------------------------------------------------------
__global__ __launch_bounds__(256) void k_out_mf(const float* __restrict__ qin,
                                                const float* __restrict__ kin,
                                                const float* __restrict__ vin,
                                                const float* __restrict__ kvws,
                                                const float* __restrict__ ksws,
                                                float* __restrict__ out) {
    __shared__ short sQ [64 * SB];   // [i][d]
    __shared__ short sKA[64 * SB];   // [j][d] -> reused as Amask [i][l]
    __shared__ short sVT[64 * SB];   // [m][l]
    __shared__ short sST[64 * SB];   // [m][d]  (S^T: ws layout is already [m][d])
    __shared__ float sKs[64];
    __shared__ float sZq[64];

    const int b = blockIdx.x, seq = b / NUMC, c = b % NUMC;
    const int n0 = seq / NHEAD, h0 = seq % NHEAD;
    const int t = threadIdx.x;
    const int gbase = ((n0 * LSEQ + c * CHUNK) * NHEAD + h0) * DDIM;
    const int lane = t & 63, w = t >> 6;
    const int nn = lane & 15, qq = lane >> 4;

    if (t < 64) sKs[t] = ksws[b * DDIM + t];

    const float* Sg = kvws + (size_t)b * DDIM * DDIM;
#pragma unroll
    for (int rep = 0; rep < 4; ++rep) {
        const int row = rep * 16 + 4 * w + qq;
        const int c4 = nn << 2;
        const int l0 = rep * 16 + 4 * w;
        float4 qv = *(const float4*)(qin + gbase + row * LSTRIDE + c4);
        float4 kk = *(const float4*)(kin + gbase + row * LSTRIDE + c4);
        float4 qp = {phi(qv.x), phi(qv.y), phi(qv.z), phi(qv.w)};
        float4 kp = {phi(kk.x), phi(kk.y), phi(kk.z), phi(kk.w)};
        *(uint2*)(sQ  + row * SB + c4) = pack4(qp);
        *(uint2*)(sKA + row * SB + c4) = pack4(kp);
        float4 sv = *(const float4*)(Sg + row * 64 + c4);     // straight copy
        *(uint2*)(sST + row * SB + c4) = pack4(sv);
        float4 vv = *(const float4*)(vin + gbase + row * LSTRIDE + c4);
        float4 vt = xpose4(vv, lane);                          // transpose V
        *(uint2*)(sVT + (c4 + qq) * SB + l0) = pack4(vt);
    }
    __syncthreads();

    // ---- Phase A ----
    const int rowA = 16 * w + nn;
    bf16x8 qf0 = *(const bf16x8*)(sQ + rowA * SB + qq * 8);
    bf16x8 qf1 = *(const bf16x8*)(sQ + rowA * SB + 32 + qq * 8);
    float am[4][4];
    float zrow[4] = {0.f, 0.f, 0.f, 0.f};
#pragma unroll
    for (int ct = 0; ct < 4; ++ct) {
        bf16x8 kf0 = *(const bf16x8*)(sKA + (16 * ct + nn) * SB + qq * 8);
        bf16x8 kf1 = *(const bf16x8*)(sKA + (16 * ct + nn) * SB + 32 + qq * 8);
        f32x4 acc = {0.f, 0.f, 0.f, 0.f};
        acc = __builtin_amdgcn_mfma_f32_16x16x32_bf16(qf0, kf0, acc, 0, 0, 0);
        acc = __builtin_amdgcn_mfma_f32_16x16x32_bf16(qf1, kf1, acc, 0, 0, 0);
#pragma unroll
        for (int r = 0; r < 4; ++r) {
            const int ri = 16 * w + 4 * qq + r, cj = 16 * ct + nn;
            const float mval = (cj <= ri) ? acc[r] : 0.f;
            am[ct][r] = mval;
            zrow[r] += mval;
        }
    }
#pragma unroll
    for (int r = 0; r < 4; ++r) {   // rowsum across the 16 col lanes
        float s = zrow[r];
        s += __shfl_xor(s, 1); s += __shfl_xor(s, 2);
        s += __shfl_xor(s, 4); s += __shfl_xor(s, 8);
        zrow[r] = s;
    }
    float zq = 0.f;                  // Qf . Ksum_prefix for row 16w+nn
#pragma unroll
    for (int j = 0; j < 8; ++j) {
        zq += bf2f(qf0[j]) * sKs[qq * 8 + j];
        zq += bf2f(qf1[j]) * sKs[32 + qq * 8 + j];
    }
    zq += __shfl_xor(zq, 16);
    zq += __shfl_xor(zq, 32);

    __syncthreads();                 // done reading sKA as K
    if (qq == 0) sZq[16 * w + nn] = zq;
#pragma unroll
    for (int ct = 0; ct < 4; ++ct)
#pragma unroll
        for (int r = 0; r < 4; ++r)
            sKA[(16 * w + 4 * qq + r) * SB + 16 * ct + nn] = (short)f2bf(am[ct][r]);
    __syncthreads();

    // ---- Phases B + C ----
    f32x4 o[4] = {{0,0,0,0},{0,0,0,0},{0,0,0,0},{0,0,0,0}};
    bf16x8 af0 = *(const bf16x8*)(sKA + rowA * SB + qq * 8);
    bf16x8 af1 = *(const bf16x8*)(sKA + rowA * SB + 32 + qq * 8);
#pragma unroll
    for (int ct = 0; ct < 4; ++ct) {
        bf16x8 vf0 = *(const bf16x8*)(sVT + (16 * ct + nn) * SB + qq * 8);
        bf16x8 vf1 = *(const bf16x8*)(sVT + (16 * ct + nn) * SB + 32 + qq * 8);
        o[ct] = __builtin_amdgcn_mfma_f32_16x16x32_bf16(af0, vf0, o[ct], 0, 0, 0);
        o[ct] = __builtin_amdgcn_mfma_f32_16x16x32_bf16(af1, vf1, o[ct], 0, 0, 0);
        bf16x8 sf0 = *(const bf16x8*)(sST + (16 * ct + nn) * SB + qq * 8);
        bf16x8 sf1 = *(const bf16x8*)(sST + (16 * ct + nn) * SB + 32 + qq * 8);
        o[ct] = __builtin_amdgcn_mfma_f32_16x16x32_bf16(qf0, sf0, o[ct], 0, 0, 0);
        o[ct] = __builtin_amdgcn_mfma_f32_16x16x32_bf16(qf1, sf1, o[ct], 0, 0, 0);
    }

#pragma unroll
    for (int r = 0; r < 4; ++r) {
        const int ri = 16 * w + 4 * qq + r;
        const float z = zrow[r] + sZq[ri] + EPSF;
        const float invz = 1.f / z;
#pragma unroll
        for (int ct = 0; ct < 4; ++ct)
            out[gbase + ri * LSTRIDE + 16 * ct + nn] = o[ct][r] * invz;
    }
}

// ---------------------------------------------------------------------------
// Fallback (tiny ws): fully sequential per-sequence scan, fp32, no workspace.
// ---------------------------------------------------------------------------
__global__ __launch_bounds__(64) void k_seq(const float* __restrict__ qin,
                                            const float* __restrict__ kin,
                                            const float* __restrict__ vin,
                                            float* __restrict__ out) {
    const int seq = blockIdx.x;
    const int n = seq / NHEAD, h = seq % NHEAD;
    const int lane = threadIdx.x;
    float Scol[DDIM];
#pragma unroll
    for (int d = 0; d < DDIM; ++d) Scol[d] = 0.0f;
    float kc = 0.0f;
    __shared__ float qk[2 * DDIM];
    int base = (n * LSEQ * NHEAD + h) * DDIM + lane;
    for (int i = 0; i < LSEQ; ++i) {
        float qval = phi(qin[base]);
        float kval = phi(kin[base]);
        float vval = vin[base];
        kc += kval;
        float zp = qval * kc;
#pragma unroll
        for (int off = 32; off > 0; off >>= 1) zp += __shfl_xor(zp, off, 64);
        float z = zp + EPSF;
        qk[2 * lane] = kval;
        qk[2 * lane + 1] = qval;
        __syncthreads();
        const float4* qk4 = (const float4*)qk;
        float acc = 0.0f;
#pragma unroll
        for (int d2 = 0; d2 < DDIM / 2; ++d2) {
            float4 t0 = qk4[d2];
            int d = 2 * d2;
            Scol[d]     += t0.x * vval;  acc += t0.y * Scol[d];
            Scol[d + 1] += t0.z * vval;  acc += t0.w * Scol[d + 1];
        }
        out[base] = acc / z;
        base += LSTRIDE;
        __syncthreads();
    }
}

// ---------------------------------------------------------------------------
extern "C" void kernel_launch(void* const* d_in, const int* in_sizes, int n_in,
                              void* d_out, int out_size, void* d_ws, size_t ws_size,
                              hipStream_t stream) {
    const float* q = (const float*)d_in[0];
    const float* k = (const float*)d_in[1];
    const float* v = (const float*)d_in[2];
    float* out = (float*)d_out;
    float* ws  = (float*)d_ws;

    const size_t need = (size_t)NH * NUMC * (DDIM * DDIM + DDIM) * sizeof(float);
    if (ws_size >= need) {
        float* kv   = ws;
        float* ksum = ws + (size_t)NH * NUMC * DDIM * DDIM;
        k_sum_mf<<<NH * NUMC, 256, 0, stream>>>(k, v, kv, ksum);
        k_scan_mm<<<NH * 16, 64, 0, stream>>>(kv, ksum);
        k_out_mf<<<NH * NUMC, 256, 0, stream>>>(q, k, v, kv, ksum, out);
    } else {
        k_seq<<<NH, 64, 0, stream>>>(q, k, v, out);
    }
}